// Round 1
// baseline (248.891 us; speedup 1.0000x reference)
//
#include <hip/hip_runtime.h>

#define LSEQ 2048
#define DIM 512
#define NH 8
#define HS 64

typedef __attribute__((ext_vector_type(8))) short short8;
typedef __attribute__((ext_vector_type(4))) float f32x4;

__device__ inline unsigned short f2bf(float f) {
  union { float f; unsigned u; } a; a.f = f;
  unsigned r = a.u + 0x7FFFu + ((a.u >> 16) & 1u);
  return (unsigned short)(r >> 16);
}

__device__ inline f32x4 mfma_bf16(short8 a, short8 b, f32x4 c) {
  return __builtin_amdgcn_mfma_f32_16x16x32_bf16(a, b, c, 0, 0, 0);
}

__device__ inline short8 ld8(const unsigned short* p) {
  return *reinterpret_cast<const short8*>(p);
}

// ---------------- fp32 -> bf16 convert ----------------
__global__ void cvt_kernel(const float* __restrict__ src, unsigned short* __restrict__ dst, int n) {
  int i = blockIdx.x * 256 + threadIdx.x;
  if (i < n) dst[i] = f2bf(src[i]);
}

// ---------------- LayerNorm: x (4096,512) f32 -> hn bf16 ----------------
__global__ __launch_bounds__(256) void ln_kernel(const float* __restrict__ x,
    const float* __restrict__ g, const float* __restrict__ bta,
    unsigned short* __restrict__ hn) {
  int row = blockIdx.x, tid = threadIdx.x;
  const float2* xr = reinterpret_cast<const float2*>(x + (size_t)row * DIM);
  float2 v = xr[tid];
  float s = v.x + v.y, sq = v.x * v.x + v.y * v.y;
#pragma unroll
  for (int off = 1; off < 64; off <<= 1) {
    s += __shfl_xor(s, off);
    sq += __shfl_xor(sq, off);
  }
  __shared__ float red[8];
  if ((tid & 63) == 0) { red[tid >> 6] = s; red[4 + (tid >> 6)] = sq; }
  __syncthreads();
  s = red[0] + red[1] + red[2] + red[3];
  sq = red[4] + red[5] + red[6] + red[7];
  float mu = s * (1.f / DIM);
  float var = sq * (1.f / DIM) - mu * mu;
  float rstd = rsqrtf(var + 1e-5f);
  float2 gg = reinterpret_cast<const float2*>(g)[tid];
  float2 bb = reinterpret_cast<const float2*>(bta)[tid];
  unsigned short h0 = f2bf((v.x - mu) * rstd * gg.x + bb.x);
  unsigned short h1 = f2bf((v.y - mu) * rstd * gg.y + bb.y);
  reinterpret_cast<unsigned int*>(hn)[(size_t)row * (DIM / 2) + tid] =
      (unsigned)h0 | ((unsigned)h1 << 16);
}

// ---------------- QKV projections: hn @ W^T + b, scattered to per-head layouts ----
__global__ __launch_bounds__(256) void qkv_kernel(const unsigned short* __restrict__ hn,
    const unsigned short* __restrict__ wqb, const unsigned short* __restrict__ wkb,
    const unsigned short* __restrict__ wvb,
    const float* __restrict__ bq, const float* __restrict__ bk, const float* __restrict__ bv,
    unsigned short* __restrict__ qo, unsigned short* __restrict__ ko,
    unsigned short* __restrict__ vT) {
  int lane = threadIdx.x & 63, widx = threadIdx.x >> 6;
  int col = lane & 15, grp = lane >> 4;
  int wgid = blockIdx.x * 4 + widx;  // 0..6143
  int mat = wgid >> 11;
  int rem = wgid & 2047;
  int m0 = (rem >> 3) * 16;
  int n0 = (rem & 7) * 64;
  const unsigned short* W = (mat == 0) ? wqb : (mat == 1) ? wkb : wvb;
  const float* bias = (mat == 0) ? bq : (mat == 1) ? bk : bv;
  f32x4 acc[4];
#pragma unroll
  for (int i = 0; i < 4; ++i) acc[i] = (f32x4){0.f, 0.f, 0.f, 0.f};
  for (int k0 = 0; k0 < DIM; k0 += 32) {
    short8 af = ld8(hn + (size_t)(m0 + col) * DIM + k0 + 8 * grp);
#pragma unroll
    for (int nt = 0; nt < 4; ++nt) {
      short8 bf = ld8(W + (size_t)(n0 + nt * 16 + col) * DIM + k0 + 8 * grp);
      acc[nt] = mfma_bf16(af, bf, acc[nt]);
    }
  }
#pragma unroll
  for (int nt = 0; nt < 4; ++nt) {
    int n = n0 + nt * 16 + col;   // feature
    int hh = n >> 6, d = n & 63;
    float bsv = bias[n];
#pragma unroll
    for (int r = 0; r < 4; ++r) {
      int m = m0 + 4 * grp + r;   // token
      float val = acc[nt][r] + bsv;
      int b = m >> 11, l = m & (LSEQ - 1);
      unsigned short hv = f2bf(val);
      if (mat == 2)
        vT[((size_t)(b * NH + hh) * HS + d) * LSEQ + l] = hv;
      else {
        unsigned short* dst = (mat == 0) ? qo : ko;
        dst[((size_t)(b * NH + hh) * LSEQ + l) * HS + d] = hv;
      }
    }
  }
}

// ---------------- fused causal attention with skewed rel bias ----------------
// one wave per 16 q-rows; S^T = K·Q^T so softmax is lane-local in m=lane&15.
__global__ __launch_bounds__(256) void attn_kernel(const unsigned short* __restrict__ q,
    const unsigned short* __restrict__ k, const unsigned short* __restrict__ vT,
    const unsigned short* __restrict__ erb, unsigned short* __restrict__ attT) {
  __shared__ float Uall[4][48 * 17];
  __shared__ unsigned int Pall[4][16 * 16];
  int lane = threadIdx.x & 63, widx = threadIdx.x >> 6;
  int mcol = lane & 15, grp = lane >> 4;
  float* U = Uall[widx];
  unsigned int* P = Pall[widx];
  int wgid = blockIdx.x * 4 + widx;  // 0..1023
  int bh = wgid >> 6;
  int pair = wgid & 63;
  int b = bh >> 3, h = bh & 7;
  const unsigned short* Qb = q + (size_t)bh * LSEQ * HS;
  const unsigned short* Kb = k + (size_t)bh * LSEQ * HS;
  const unsigned short* Vb = vT + (size_t)bh * HS * LSEQ;
  const unsigned short* Eb = erb + (size_t)h * LSEQ * HS;

  for (int rep = 0; rep < 2; ++rep) {
    int qt = rep ? (127 - pair) : pair;
    int qi0 = qt * 16;
    short8 qf0 = ld8(Qb + (size_t)(qi0 + mcol) * HS + 8 * grp);
    short8 qf1 = ld8(Qb + (size_t)(qi0 + mcol) * HS + 32 + 8 * grp);
    f32x4 o[4];
#pragma unroll
    for (int i = 0; i < 4; ++i) o[i] = (f32x4){0.f, 0.f, 0.f, 0.f};
    float mrun = -3e38f, lsum = 0.f;
    int nkb = ((qi0 + 15) >> 5) + 1;
    for (int kb = 0; kb < nkb; ++kb) {
      int kj0 = kb * 32;
      // S^T tiles: st[t][r] = K[kj0+16t+4g+r] . Q[qi0+mcol]
      f32x4 st[2];
#pragma unroll
      for (int t = 0; t < 2; ++t) {
        short8 kf0 = ld8(Kb + (size_t)(kj0 + 16 * t + mcol) * HS + 8 * grp);
        short8 kf1 = ld8(Kb + (size_t)(kj0 + 16 * t + mcol) * HS + 32 + 8 * grp);
        f32x4 a = (f32x4){0.f, 0.f, 0.f, 0.f};
        a = mfma_bf16(kf0, qf0, a);
        a = mfma_bf16(kf1, qf1, a);
        st[t] = a;
      }
      // rel-bias band: U^T[j][m] = Er[e0+j] . Q[qi0+m],  j in [0,48)
      int e0 = 2032 - qi0 + kj0;
#pragma unroll
      for (int jt = 0; jt < 3; ++jt) {
        int er = e0 + 16 * jt + mcol;
        if (er > 2047) er = 2047;   // clamped rows only feed masked entries
        short8 ef0 = ld8(Eb + (size_t)er * HS + 8 * grp);
        short8 ef1 = ld8(Eb + (size_t)er * HS + 32 + 8 * grp);
        f32x4 u = (f32x4){0.f, 0.f, 0.f, 0.f};
        u = mfma_bf16(ef0, qf0, u);
        u = mfma_bf16(ef1, qf1, u);
#pragma unroll
        for (int r = 0; r < 4; ++r)
          U[(16 * jt + 4 * grp + r) * 17 + mcol] = u[r];
      }
      asm volatile("s_waitcnt lgkmcnt(0)" ::: "memory");
      __builtin_amdgcn_sched_barrier(0);
      // logits + causal mask + skew gather rel[n][m] = U[n-m+15][m]
      float lt[2][4];
      float pmax = -3e38f;
#pragma unroll
      for (int t = 0; t < 2; ++t) {
#pragma unroll
        for (int r = 0; r < 4; ++r) {
          int n = 16 * t + 4 * grp + r;
          float val = st[t][r] * 0.125f + U[(n - mcol + 15) * 17 + mcol];
          if (kj0 + n > qi0 + mcol) val = -3e38f;
          lt[t][r] = val;
          pmax = fmaxf(pmax, val);
        }
      }
      pmax = fmaxf(pmax, __shfl_xor(pmax, 16));
      pmax = fmaxf(pmax, __shfl_xor(pmax, 32));
      float mnew = fmaxf(mrun, pmax);
      float alpha = __expf(mrun - mnew);
      float p[2][4];
      float psum = 0.f;
#pragma unroll
      for (int t = 0; t < 2; ++t) {
#pragma unroll
        for (int r = 0; r < 4; ++r) {
          p[t][r] = __expf(lt[t][r] - mnew);
          psum += p[t][r];
        }
      }
      psum += __shfl_xor(psum, 16);
      psum += __shfl_xor(psum, 32);
      lsum = lsum * alpha + psum;
      mrun = mnew;
#pragma unroll
      for (int i = 0; i < 4; ++i) o[i] *= alpha;
      // P^T -> B-frag via LDS: store P[m][n] row-major bf16
#pragma unroll
      for (int t = 0; t < 2; ++t) {
        unsigned w0 = (unsigned)f2bf(p[t][0]) | ((unsigned)f2bf(p[t][1]) << 16);
        unsigned w1 = (unsigned)f2bf(p[t][2]) | ((unsigned)f2bf(p[t][3]) << 16);
        P[mcol * 16 + 8 * t + 2 * grp] = w0;
        P[mcol * 16 + 8 * t + 2 * grp + 1] = w1;
      }
      asm volatile("s_waitcnt lgkmcnt(0)" ::: "memory");
      __builtin_amdgcn_sched_barrier(0);
      short8 pf = *reinterpret_cast<const short8*>(P + mcol * 16 + 4 * grp);
      // O^T += V^T . P^T
#pragma unroll
      for (int dt = 0; dt < 4; ++dt) {
        short8 vf = ld8(Vb + (size_t)(dt * 16 + mcol) * LSEQ + kj0 + 8 * grp);
        o[dt] = mfma_bf16(vf, pf, o[dt]);
      }
    }
    float inv = 1.f / lsum;
#pragma unroll
    for (int dt = 0; dt < 4; ++dt) {
#pragma unroll
      for (int r = 0; r < 4; ++r) {
        int d = dt * 16 + 4 * grp + r;
        attT[((size_t)(b * LSEQ) + qi0 + mcol) * DIM + h * HS + d] =
            f2bf(o[dt][r] * inv);
      }
    }
  }
}

// ---------------- output projection: attT @ wo^T + bo -> fp32 ----------------
__global__ __launch_bounds__(256) void out_kernel(const unsigned short* __restrict__ attT,
    const unsigned short* __restrict__ wob, const float* __restrict__ bo,
    float* __restrict__ out) {
  int lane = threadIdx.x & 63, widx = threadIdx.x >> 6;
  int col = lane & 15, grp = lane >> 4;
  int wgid = blockIdx.x * 4 + widx;  // 0..2047
  int m0 = (wgid >> 3) * 16;
  int n0 = (wgid & 7) * 64;
  f32x4 acc[4];
#pragma unroll
  for (int i = 0; i < 4; ++i) acc[i] = (f32x4){0.f, 0.f, 0.f, 0.f};
  for (int k0 = 0; k0 < DIM; k0 += 32) {
    short8 af = ld8(attT + (size_t)(m0 + col) * DIM + k0 + 8 * grp);
#pragma unroll
    for (int nt = 0; nt < 4; ++nt) {
      short8 bf = ld8(wob + (size_t)(n0 + nt * 16 + col) * DIM + k0 + 8 * grp);
      acc[nt] = mfma_bf16(af, bf, acc[nt]);
    }
  }
#pragma unroll
  for (int nt = 0; nt < 4; ++nt) {
    int n = n0 + nt * 16 + col;
    float bsv = bo[n];
#pragma unroll
    for (int r = 0; r < 4; ++r) {
      int m = m0 + 4 * grp + r;
      out[(size_t)m * DIM + n] = acc[nt][r] + bsv;
    }
  }
}

extern "C" void kernel_launch(void* const* d_in, const int* in_sizes, int n_in,
                              void* d_out, int out_size, void* d_ws, size_t ws_size,
                              hipStream_t stream) {
  const float* x    = (const float*)d_in[0];
  // d_in[1] = mask (causal triu, hardcoded)
  const float* ln_g = (const float*)d_in[2];
  const float* ln_b = (const float*)d_in[3];
  const float* wq   = (const float*)d_in[4];
  const float* bq   = (const float*)d_in[5];
  const float* wk   = (const float*)d_in[6];
  const float* bk   = (const float*)d_in[7];
  const float* wv   = (const float*)d_in[8];
  const float* bv   = (const float*)d_in[9];
  const float* wo   = (const float*)d_in[10];
  const float* bo   = (const float*)d_in[11];
  const float* Er   = (const float*)d_in[12];
  float* out = (float*)d_out;

  char* ws = (char*)d_ws;
  unsigned short* hn   = (unsigned short*)(ws);                    // 4 MiB
  unsigned short* qb   = (unsigned short*)(ws + (4u << 20));       // 4 MiB
  unsigned short* kb   = (unsigned short*)(ws + (8u << 20));       // 4 MiB
  unsigned short* vT   = (unsigned short*)(ws + (12u << 20));      // 4 MiB
  unsigned short* erb  = (unsigned short*)(ws + (16u << 20));      // 2 MiB
  unsigned short* attT = (unsigned short*)(ws + (18u << 20));      // 4 MiB
  unsigned short* wqb  = (unsigned short*)(ws + (22u << 20));
  unsigned short* wkb  = wqb + 512 * 512;
  unsigned short* wvb  = wkb + 512 * 512;
  unsigned short* wob  = wvb + 512 * 512;

  cvt_kernel<<<4096, 256, 0, stream>>>(Er, erb, NH * LSEQ * HS);
  cvt_kernel<<<1024, 256, 0, stream>>>(wq, wqb, DIM * DIM);
  cvt_kernel<<<1024, 256, 0, stream>>>(wk, wkb, DIM * DIM);
  cvt_kernel<<<1024, 256, 0, stream>>>(wv, wvb, DIM * DIM);
  cvt_kernel<<<1024, 256, 0, stream>>>(wo, wob, DIM * DIM);
  ln_kernel<<<4096, 256, 0, stream>>>(x, ln_g, ln_b, hn);
  qkv_kernel<<<1536, 256, 0, stream>>>(hn, wqb, wkb, wvb, bq, bk, bv, qb, kb, vT);
  attn_kernel<<<256, 256, 0, stream>>>(qb, kb, vT, erb, attT);
  out_kernel<<<512, 256, 0, stream>>>(attT, wob, bo, out);
}